// Round 6
// baseline (660.671 us; speedup 1.0000x reference)
//
#include <hip/hip_runtime.h>
#include <hip/hip_bf16.h>
#include <stdint.h>

#define T_LEN 4096
#define B_SZ  8
#define D_IN  1024
#define D_M   256
#define N_C   157

typedef __attribute__((ext_vector_type(8))) short short8;
typedef __attribute__((ext_vector_type(4))) float floatx4;

static __device__ __forceinline__ unsigned short f2bf(float f) {
  unsigned u = __float_as_uint(f);
  u += 0x7FFFu + ((u >> 16) & 1u);
  return (unsigned short)(u >> 16);
}
static __device__ __forceinline__ float bf2f(unsigned short h) {
  return __uint_as_float(((unsigned)h) << 16);
}

// async global->LDS, 16B/lane; LDS dest = wave-uniform base + lane*16
static __device__ __forceinline__ void gl_lds16(const unsigned short* g,
                                                unsigned short* l) {
  __builtin_amdgcn_global_load_lds(
      (const __attribute__((address_space(1))) unsigned int*)g,
      (__attribute__((address_space(3))) unsigned int*)l, 16, 0, 0);
}

// ---------------- weight prep: fp32 -> bf16, 22 segments ------------------
struct WSeg { const float* src; int n; int off; };
struct WPrepArgs { WSeg seg[22]; };

__global__ void wprep_kernel(WPrepArgs a, unsigned short* __restrict__ wbuf) {
  WSeg s = a.seg[blockIdx.x];
  for (int i = (blockIdx.y << 8) + threadIdx.x; i < s.n; i += (gridDim.y << 8))
    wbuf[s.off + i] = f2bf(s.src[i]);
}

// ---------------- x (B,DIN,T) f32 -> xT (B,T,DIN) bf16 --------------------
__global__ void transpose_xT(const float* __restrict__ x,
                             unsigned short* __restrict__ xT) {
  __shared__ float tile[64][65];
  const int t0 = blockIdx.x << 6;
  const int i0 = blockIdx.y << 6;
  const int b  = blockIdx.z;
  const int tid = threadIdx.x;
  {
    const int row = tid >> 2;
    const int cc  = (tid & 3) << 4;
    const float* src = x + ((size_t)b * D_IN + (i0 + row)) * T_LEN + t0 + cc;
#pragma unroll
    for (int p = 0; p < 4; ++p) {
      float4 v = *(const float4*)(src + p * 4);
      tile[row][cc + p * 4 + 0] = v.x;
      tile[row][cc + p * 4 + 1] = v.y;
      tile[row][cc + p * 4 + 2] = v.z;
      tile[row][cc + p * 4 + 3] = v.w;
    }
  }
  __syncthreads();
#pragma unroll
  for (int it = 0; it < 2; ++it) {
    const int task = tid + (it << 8);
    const int tr = task >> 3;
    const int ic = (task & 7) << 3;
    short8 o;
#pragma unroll
    for (int j = 0; j < 8; ++j) o[j] = (short)f2bf(tile[ic + j][tr]);
    *(short8*)(xT + ((size_t)b * T_LEN + (t0 + tr)) * D_IN + i0 + ic) = o;
  }
}

// ---------------- plain MFMA GEMM (for bottle0 and final) -----------------
// normal: C(B,T,Mw) = A(B,T,K) * W(Mw,K)^T, bf16 out
// SWAP_CT: A=W rows, B=act rows; f32 out (B,Mw,T) channel-major
template<bool HAS_BIAS, bool HAS_MASK, bool SWAP_CT>
__global__ __launch_bounds__(256)
void gemm_kernel(const unsigned short* __restrict__ Xact,
                 const unsigned short* __restrict__ W,
                 const float* __restrict__ bias,
                 const float* __restrict__ mask,
                 float* __restrict__ outF,
                 unsigned short* __restrict__ outB,
                 int K, int Mw) {
  __shared__ unsigned short sA[2][64 * 64];
  __shared__ unsigned short sB[2][128 * 64];

  const int bx = blockIdx.x;
  const int t0 = blockIdx.y << (SWAP_CT ? 7 : 6);
  const int b  = blockIdx.z;
  const int tid  = threadIdx.x;
  const int wv   = tid >> 6;
  const int lane = tid & 63;
  const int wn   = wv << 5;
  const int fm   = lane & 15;
  const int fq   = lane >> 4;
  const int lrow = lane >> 3;
  const int cbg8 = (((lane & 7) ^ lrow) << 3);

  const unsigned short* Xb = Xact + (size_t)b * T_LEN * (size_t)K;
  const unsigned short* srcA =
      SWAP_CT ? (W + (size_t)(bx << 6) * K) : (Xb + (size_t)t0 * K);
  const unsigned short* srcB =
      SWAP_CT ? (Xb + (size_t)t0 * K) : (W + (size_t)(bx << 7) * K);

  const floatx4 fz = {0.f, 0.f, 0.f, 0.f};
  floatx4 acc[4][2];
#pragma unroll
  for (int i = 0; i < 4; ++i)
#pragma unroll
    for (int j = 0; j < 2; ++j) acc[i][j] = fz;

  auto stage = [&](int kk, int bufi) {
#pragma unroll
    for (int p = 0; p < 2; ++p) {
      const int slot = (p << 2) + wv;
      gl_lds16(srcA + (size_t)((slot << 3) + lrow) * K + kk + cbg8,
               &sA[bufi][slot * 512]);
    }
#pragma unroll
    for (int p = 0; p < 4; ++p) {
      const int slot = (p << 2) + wv;
      gl_lds16(srcB + (size_t)((slot << 3) + lrow) * K + kk + cbg8,
               &sB[bufi][slot * 512]);
    }
  };

  const int niter = K >> 6;
  stage(0, 0);
  for (int it = 0; it < niter; ++it) {
    const int p = it & 1;
    __syncthreads();
    if (it + 1 < niter) stage((it + 1) << 6, 1 - p);
#pragma unroll
    for (int ks = 0; ks < 64; ks += 32) {
      const int cbase = ((fq + (ks >> 3)) ^ (fm & 7)) << 3;
      short8 af[4], bfr[2];
#pragma unroll
      for (int i = 0; i < 4; ++i)
        af[i] = *(short8*)&sA[p][(((i << 4) + fm) << 6) + cbase];
#pragma unroll
      for (int j = 0; j < 2; ++j)
        bfr[j] = *(short8*)&sB[p][((wn + (j << 4) + fm) << 6) + cbase];
#pragma unroll
      for (int i = 0; i < 4; ++i)
#pragma unroll
        for (int j = 0; j < 2; ++j)
          acc[i][j] = __builtin_amdgcn_mfma_f32_16x16x32_bf16(
              af[i], bfr[j], acc[i][j], 0, 0, 0);
    }
  }

  if constexpr (SWAP_CT) {
#pragma unroll
    for (int i = 0; i < 4; ++i) {
#pragma unroll
      for (int r = 0; r < 4; ++r) {
        const int o = (bx << 6) + (i << 4) + (fq << 2) + r;
        if (o >= Mw) continue;
        const float bi = HAS_BIAS ? bias[o] : 0.0f;
#pragma unroll
        for (int j = 0; j < 2; ++j) {
          const int t = t0 + wn + (j << 4) + fm;
          float val = acc[i][j][r] + bi;
          if (HAS_MASK) val *= mask[(size_t)b * T_LEN + t];
          outF[((size_t)b * Mw + o) * T_LEN + t] = val;
        }
      }
    }
  } else {
#pragma unroll
    for (int i = 0; i < 4; ++i) {
#pragma unroll
      for (int j = 0; j < 2; ++j) {
        const int co = (bx << 7) + wn + (j << 4) + fm;
        if (co >= Mw) continue;
        const float bi = HAS_BIAS ? bias[co] : 0.0f;
#pragma unroll
        for (int r = 0; r < 4; ++r) {
          const int t = t0 + (i << 4) + (fq << 2) + r;
          float val = acc[i][j][r] + bi;
          if (HAS_MASK) val *= mask[(size_t)b * T_LEN + t];
          outB[((size_t)b * T_LEN + t) * (size_t)Mw + co] = f2bf(val);
        }
      }
    }
  }
}

// ---------------- fused layer: qkv GEMM + 3-tap attn + bottle GEMM --------
// block = 64 t-rows (+16 halo each side). LDS (shorts):
//  xh   [96][256]  swizzled (gl_lds-staged x rows)            24576
//  hbuf [64][264]  attn output, +8 pad                        16896
//  chunk 3x[96][72] q/k/v 64-ch chunk, +8 pad (Phase C: Wb dbuf) 20736
//  wst  2x[64][64] swizzled W staging dbuf                     8192
__global__ __launch_bounds__(256)
void layer_kernel(const unsigned short* __restrict__ outPrev,
                  const unsigned short* __restrict__ Wall,  // 768x256 [q;k;v]
                  const unsigned short* __restrict__ Wb,    // 256x256
                  const float* __restrict__ bias,
                  const float* __restrict__ mask,
                  unsigned short* __restrict__ outNext,
                  int dil) {
  __shared__ unsigned short lds[70400];
  unsigned short* xh    = lds;             // 24576
  unsigned short* hbuf  = lds + 24576;     // 16896
  unsigned short* chunk = lds + 41472;     // 20736
  unsigned short* wst   = lds + 62208;     // 8192

  const int t0 = blockIdx.x << 6;
  const int b  = blockIdx.y;
  const int tid  = threadIdx.x;
  const int wv   = tid >> 6;
  const int lane = tid & 63;
  const int fm   = lane & 15;
  const int fq   = lane >> 4;
  const int wh   = wv >> 1;   // Phase B m-half
  const int nh   = wv & 1;    // Phase B n-half

  const unsigned short* src = outPrev + (size_t)b * T_LEN * 256;

  // ---- Phase A: stage xh rows = out[t0-16 .. t0+79], clamped then zeroed
  // 96 rows x 512B: 48 slots of (2 rows / 1024B) -> 12 passes x 4 waves
#pragma unroll
  for (int p = 0; p < 12; ++p) {
    const int slot = (p << 2) + wv;               // 0..47
    const int row  = (slot << 1) + (lane >> 5);   // 0..95
    int t = t0 - 16 + row;
    t = t < 0 ? 0 : (t >= T_LEN ? T_LEN - 1 : t);
    const int kb = (lane & 31) ^ (row & 7);
    gl_lds16(src + (size_t)t * 256 + (kb << 3), xh + (slot << 9));
  }
  __syncthreads();
  if (t0 == 0) {
    *(short8*)&xh[tid << 4] = short8{0,0,0,0,0,0,0,0};
    *(short8*)&xh[(tid << 4) + 8] = short8{0,0,0,0,0,0,0,0};
  }
  if (t0 == T_LEN - 64) {
    *(short8*)&xh[20480 + (tid << 4)] = short8{0,0,0,0,0,0,0,0};
    *(short8*)&xh[20480 + (tid << 4) + 8] = short8{0,0,0,0,0,0,0,0};
  }
  __syncthreads();

  // ---- Phase B: per 64-ch chunk j: q,k,v sub-GEMMs (96x64, K=256) + attn
#pragma unroll 1
  for (int j = 0; j < 4; ++j) {
#pragma unroll 1
    for (int sec = 0; sec < 3; ++sec) {
      const unsigned short* Wsec = Wall + (size_t)((sec << 8) + (j << 6)) * 256;
      // stage kt=0
#pragma unroll
      for (int p = 0; p < 2; ++p) {
        const int slot = (p << 2) + wv;
        const int rw = (slot << 3) + (lane >> 3);
        const int kb = (lane & 7) ^ (lane >> 3);
        gl_lds16(Wsec + (size_t)rw * 256 + (kb << 3), wst + (slot << 9));
      }
      floatx4 accB[3][2];
#pragma unroll
      for (int i = 0; i < 3; ++i)
#pragma unroll
        for (int jj = 0; jj < 2; ++jj) accB[i][jj] = floatx4{0.f,0.f,0.f,0.f};

      for (int kt = 0; kt < 4; ++kt) {
        __syncthreads();
        if (kt < 3) {
          const int nb = (kt + 1) & 1;
#pragma unroll
          for (int p = 0; p < 2; ++p) {
            const int slot = (p << 2) + wv;
            const int rw = (slot << 3) + (lane >> 3);
            const int kb = (lane & 7) ^ (lane >> 3);
            gl_lds16(Wsec + (size_t)rw * 256 + ((kt + 1) << 6) + (kb << 3),
                     wst + (nb << 12) + (slot << 9));
          }
        }
        const unsigned short* wb = wst + ((kt & 1) << 12);
#pragma unroll
        for (int ks = 0; ks < 64; ks += 32) {
          short8 af[3], bfr[2];
#pragma unroll
          for (int i = 0; i < 3; ++i) {
            const int row = 48 * wh + (i << 4) + fm;
            const int cb = ((kt << 3) + (ks >> 3) + fq) ^ (fm & 7);
            af[i] = *(short8*)&xh[(row << 8) + (cb << 3)];
          }
#pragma unroll
          for (int jj = 0; jj < 2; ++jj) {
            const int nr = (nh << 5) + (jj << 4) + fm;
            const int cb = ((ks >> 3) + fq) ^ (fm & 7);
            bfr[jj] = *(short8*)&wb[(nr << 6) + (cb << 3)];
          }
#pragma unroll
          for (int i = 0; i < 3; ++i)
#pragma unroll
            for (int jj = 0; jj < 2; ++jj)
              accB[i][jj] = __builtin_amdgcn_mfma_f32_16x16x32_bf16(
                  af[i], bfr[jj], accB[i][jj], 0, 0, 0);
        }
      }
      // write q/k/v chunk (96x64, row pad 72)
#pragma unroll
      for (int i = 0; i < 3; ++i)
#pragma unroll
        for (int jj = 0; jj < 2; ++jj)
#pragma unroll
          for (int r = 0; r < 4; ++r) {
            const int row = 48 * wh + (i << 4) + (fq << 2) + r;
            const int col = (nh << 5) + (jj << 4) + fm;
            chunk[sec * 6912 + row * 72 + col] = f2bf(accB[i][jj][r]);
          }
    }
    __syncthreads();
    // attention for ch-chunk j -> hbuf[:, 64j..64j+63]
#pragma unroll
    for (int p = 0; p < 2; ++p) {
      const int task = (p << 8) + tid;
      const int tr = task >> 3;
      const int c8 = (task & 7) << 3;
      const int rq = (16 + tr) * 72 + c8;
      short8 qv = *(short8*)&chunk[rq];
      short8 kc = *(short8*)&chunk[6912 + rq];
      short8 vc = *(short8*)&chunk[13824 + rq];
      short8 km = *(short8*)&chunk[6912 + (16 + tr - dil) * 72 + c8];
      short8 kp = *(short8*)&chunk[6912 + (16 + tr + dil) * 72 + c8];
      short8 vm = *(short8*)&chunk[13824 + (16 + tr - dil) * 72 + c8];
      short8 vp = *(short8*)&chunk[13824 + (16 + tr + dil) * 72 + c8];
      short8 o;
#pragma unroll
      for (int e = 0; e < 8; ++e) {
        float q  = bf2f((unsigned short)qv[e]);
        float s0 = q * bf2f((unsigned short)km[e]);
        float s1 = q * bf2f((unsigned short)kc[e]);
        float s2 = q * bf2f((unsigned short)kp[e]);
        float mx = fmaxf(s0, fmaxf(s1, s2));
        float e0 = __expf(s0 - mx), e1 = __expf(s1 - mx), e2 = __expf(s2 - mx);
        float num = e0 * bf2f((unsigned short)vm[e]) +
                    e1 * bf2f((unsigned short)vc[e]) +
                    e2 * bf2f((unsigned short)vp[e]);
        float r = num / (e0 + e1 + e2);
        o[e] = (short)f2bf(fmaxf(r, 0.0f));
      }
      *(short8*)&hbuf[tr * 264 + (j << 6) + c8] = o;
    }
    __syncthreads();
  }

  // ---- Phase C: out = (x + Wb @ h + bb) * mask   (64x256, K=256, BK=32)
  floatx4 accC[4][4];
#pragma unroll
  for (int i = 0; i < 4; ++i)
#pragma unroll
    for (int jj = 0; jj < 4; ++jj) accC[i][jj] = floatx4{0.f,0.f,0.f,0.f};

#pragma unroll
  for (int p = 0; p < 4; ++p) {   // stage kt=0 into chunk buf0
    const int slot = (p << 2) + wv;
    const int rw = (slot << 4) + (lane >> 2);
    gl_lds16(Wb + (size_t)rw * 256 + ((lane & 3) << 3), chunk + (slot << 9));
  }
  for (int kt = 0; kt < 8; ++kt) {
    __syncthreads();
    if (kt < 7) {
      const int nb = (kt + 1) & 1;
#pragma unroll
      for (int p = 0; p < 4; ++p) {
        const int slot = (p << 2) + wv;
        const int rw = (slot << 4) + (lane >> 2);
        gl_lds16(Wb + (size_t)rw * 256 + ((kt + 1) << 5) + ((lane & 3) << 3),
                 chunk + (nb << 13) + (slot << 9));
      }
    }
    const unsigned short* cbuf = chunk + ((kt & 1) << 13);
    short8 af[4], bfr[4];
#pragma unroll
    for (int i = 0; i < 4; ++i) {
      const int row = (i << 4) + fm;
      af[i] = *(short8*)&hbuf[row * 264 + (kt << 5) + (fq << 3)];
    }
#pragma unroll
    for (int jj = 0; jj < 4; ++jj) {
      const int nr = (wv << 6) + (jj << 4) + fm;
      bfr[jj] = *(short8*)&cbuf[(nr << 5) + (fq << 3)];
    }
#pragma unroll
    for (int i = 0; i < 4; ++i)
#pragma unroll
      for (int jj = 0; jj < 4; ++jj)
        accC[i][jj] = __builtin_amdgcn_mfma_f32_16x16x32_bf16(
            af[i], bfr[jj], accC[i][jj], 0, 0, 0);
  }

  // epilogue: + bias + resid(xh) , * mask, store bf16
#pragma unroll
  for (int i = 0; i < 4; ++i)
#pragma unroll
    for (int jj = 0; jj < 4; ++jj) {
      const int co = (wv << 6) + (jj << 4) + fm;
      const float bi = bias[co];
#pragma unroll
      for (int r = 0; r < 4; ++r) {
        const int tl = (i << 4) + (fq << 2) + r;
        const int xr = 16 + tl;
        float val = accC[i][jj][r] + bi;
        val += bf2f(xh[(xr << 8) + ((((co >> 3)) ^ (xr & 7)) << 3) + (co & 7)]);
        val *= mask[(size_t)b * T_LEN + t0 + tl];
        outNext[((size_t)b * T_LEN + t0 + tl) * 256 + co] = f2bf(val);
      }
    }
}

// ---------------- launch ---------------------------------------------------
extern "C" void kernel_launch(void* const* d_in, const int* in_sizes, int n_in,
                              void* d_out, int out_size, void* d_ws, size_t ws_size,
                              hipStream_t stream) {
  const float* x    = (const float*)d_in[0];
  const float* mask = (const float*)d_in[1];

  char* ws = (char*)d_ws;
  unsigned short* xT   = (unsigned short*)ws;                 // 64 MB
  unsigned short* out0 = (unsigned short*)(ws + 67108864);    // 16 MB
  unsigned short* out1 = (unsigned short*)(ws + 83886080);    // 16 MB
  unsigned short* wbuf = (unsigned short*)(ws + 100663296);   // ~3.3 MB

  const int WB0  = 0;        // 256x1024
  const int WQKV = 262144;   // 5 x 768x256 stacked [wq;wk;wv]
  const int WBT  = 1245184;  // 5 x 256x256
  const int WB6  = 1572864;  // 157x256 (+pad reads to 192)

  WPrepArgs pa;
  int si = 0;
  pa.seg[si++] = { (const float*)d_in[2], 262144, WB0 };
  for (int l = 0; l < 5; ++l) {
    int bi = 4 + l * 5;
    pa.seg[si++] = { (const float*)d_in[bi + 0], 65536, WQKV + l * 196608 };
    pa.seg[si++] = { (const float*)d_in[bi + 1], 65536, WQKV + l * 196608 + 65536 };
    pa.seg[si++] = { (const float*)d_in[bi + 2], 65536, WQKV + l * 196608 + 131072 };
    pa.seg[si++] = { (const float*)d_in[bi + 3], 65536, WBT + l * 65536 };
  }
  pa.seg[si++] = { (const float*)d_in[29], 40192, WB6 };

  wprep_kernel<<<dim3(22, 64), 256, 0, stream>>>(pa, wbuf);
  transpose_xT<<<dim3(64, 16, 8), 256, 0, stream>>>(x, xT);

  // bottle0: out0 = w0 @ x + b0 (bf16)
  gemm_kernel<true, false, false>
      <<<dim3(2, 64, 8), 256, 0, stream>>>(
          xT, wbuf + WB0, (const float*)d_in[3], mask, nullptr, out0, 1024, 256);

  const int dils[5] = {1, 2, 4, 8, 16};
  unsigned short* pp[2] = { out0, out1 };
  for (int l = 0; l < 5; ++l) {
    int bi = 4 + l * 5;
    layer_kernel<<<dim3(64, 8), 256, 0, stream>>>(
        pp[l & 1], wbuf + WQKV + l * 196608, wbuf + WBT + l * 65536,
        (const float*)d_in[bi + 4], mask, pp[(l + 1) & 1], dils[l]);
  }

  // final: d_out(B,157,T) = (w6 @ out + b6) * mask  (swapped, f32 CT store)
  gemm_kernel<true, true, true>
      <<<dim3(3, 32, 8), 256, 0, stream>>>(
          pp[1], wbuf + WB6, (const float*)d_in[30], mask,
          (float*)d_out, nullptr, 256, 157);
}